// Round 6
// baseline (865.001 us; speedup 1.0000x reference)
//
#include <hip/hip_runtime.h>
#include <hip/hip_bf16.h>

typedef __attribute__((ext_vector_type(8))) short short8;
typedef __attribute__((ext_vector_type(4))) float f32x4;
typedef __attribute__((ext_vector_type(4))) unsigned int u32x4;

#define LOG2E 1.44269504088896f
// R6: measurement round — k_stats and k_attn_mm bodies repeated REP times
// (results scaled by 1/REP, exact) to force them above the harness-fill
// floor in the rocprof top-5. Remove for production.
#define REP 8
#define REPSCALE 0.125f

__device__ __forceinline__ float bf2f(unsigned short b) {
    return __uint_as_float(((unsigned)b) << 16);
}
__device__ __forceinline__ unsigned short f2bf(float f) {
    __hip_bfloat16 h = __float2bfloat16(f);
    return __builtin_bit_cast(unsigned short, h);
}

// Kernel 1: seq_fts = x@W1 + b1 (f32, bf16 store) + F1/F2 row-dots via shuffle reduce.
__global__ __launch_bounds__(256) void k_feats(
    const float* __restrict__ x, const float* __restrict__ W1,
    const float* __restrict__ b1,
    const float* __restrict__ a1, const float* __restrict__ ba1,
    const float* __restrict__ a2, const float* __restrict__ ba2,
    unsigned short* __restrict__ seqbf,
    float* __restrict__ F1, float* __restrict__ F2)
{
    const int t = threadIdx.x, lane = t & 63;
    const int w = __builtin_amdgcn_readfirstlane(t >> 6);
    float W1r[64];
    #pragma unroll
    for (int c = 0; c < 64; ++c) W1r[c] = W1[c * 64 + lane];
    const float bias = b1[lane];
    const float a1l = a1[lane], a2l = a2[lane];
    const float bb1 = ba1[0], bb2 = ba2[0];
    const int row0 = (blockIdx.x * 4 + w) * 8;
    #pragma unroll
    for (int r = 0; r < 8; ++r) {
        const int row = row0 + r;
        const float* __restrict__ xr = x + (size_t)row * 64;
        float acc = bias;
        #pragma unroll
        for (int c = 0; c < 64; ++c) acc = fmaf(xr[c], W1r[c], acc);
        seqbf[(size_t)row * 64 + lane] = f2bf(acc);
        float r1 = acc * a1l;
        float r2 = acc * a2l;
        #pragma unroll
        for (int off = 32; off; off >>= 1) {
            r1 += __shfl_xor(r1, off);
            r2 += __shfl_xor(r2, off);
        }
        if (lane == 0) {
            F1[row] = LOG2E * (r1 + bb1);
            F2[row] = LOG2E * (r2 + bb2);
        }
    }
}

// Kernel 2: read adj once; bitmask + per-block partial column sums. (R5 structure,
// amplified REP x for measurement.)
__global__ __launch_bounds__(256) void k_stats(
    const int* __restrict__ adj, const float* __restrict__ F1,
    const float* __restrict__ F2, float* __restrict__ Spart,
    unsigned long long* __restrict__ mask, int N, int BN)
{
    __shared__ unsigned long long lds_mask[64][16];
    const int t = threadIdx.x, lane = t & 63;
    const int w = __builtin_amdgcn_readfirstlane(t >> 6);
    const int b = blockIdx.z;
    const int i0 = blockIdx.x * 64;
    const int jbase = blockIdx.y * 1024 + t * 4;
    const int* __restrict__ adjb = adj + (size_t)b * N * N;
    const float* __restrict__ F2b = F2 + b * N;
    const float4 f1v = *(const float4*)(F1 + b * N + jbase);
    float acc0 = 0.f, acc1 = 0.f, acc2 = 0.f, acc3 = 0.f;
    #pragma unroll 1
    for (int rep = 0; rep < REP; ++rep) {
        #pragma unroll 8
        for (int ii = 0; ii < 64; ++ii) {
            const int i = i0 + ii;
            const int4 a = *(const int4*)(adjb + (size_t)i * N + jbase);
            const float f2i = F2b[i];
            const unsigned long long m0 = __ballot(a.x > 0);
            const unsigned long long m1 = __ballot(a.y > 0);
            const unsigned long long m2 = __ballot(a.z > 0);
            const unsigned long long m3 = __ballot(a.w > 0);
            float u, mx;
            u = f1v.x + f2i; mx = fmaxf(u, 0.01f * u);
            acc0 += (a.x > 0) ? __builtin_amdgcn_exp2f(mx) : 0.f;
            u = f1v.y + f2i; mx = fmaxf(u, 0.01f * u);
            acc1 += (a.y > 0) ? __builtin_amdgcn_exp2f(mx) : 0.f;
            u = f1v.z + f2i; mx = fmaxf(u, 0.01f * u);
            acc2 += (a.z > 0) ? __builtin_amdgcn_exp2f(mx) : 0.f;
            u = f1v.w + f2i; mx = fmaxf(u, 0.01f * u);
            acc3 += (a.w > 0) ? __builtin_amdgcn_exp2f(mx) : 0.f;
            if (lane == 0) {
                lds_mask[ii][w * 4 + 0] = m0;
                lds_mask[ii][w * 4 + 1] = m1;
                lds_mask[ii][w * 4 + 2] = m2;
                lds_mask[ii][w * 4 + 3] = m3;
            }
        }
    }
    float4 s4;
    s4.x = acc0 * REPSCALE; s4.y = acc1 * REPSCALE;
    s4.z = acc2 * REPSCALE; s4.w = acc3 * REPSCALE;
    *(float4*)(Spart + (size_t)blockIdx.x * BN + b * N + jbase) = s4;
    __syncthreads();
    {
        const int ii = t >> 2, q = t & 3;
        unsigned long long* __restrict__ maskb = mask + (size_t)b * N * 64;
        unsigned long long* dst = maskb + (size_t)(i0 + ii) * 64 + blockIdx.y * 16 + q * 4;
        const unsigned long long* src = &lds_mask[ii][q * 4];
        dst[0] = src[0]; dst[1] = src[1]; dst[2] = src[2]; dst[3] = src[3];
    }
}

// Kernel 3: S = sum of Spart partials; seqTg[b][f][j] = seqbf[b][j][f] / S[b,j]
__global__ __launch_bounds__(256) void k_transpose(
    const unsigned short* __restrict__ seqbf, const float* __restrict__ Spart,
    unsigned short* __restrict__ seqTg, int N, int BN, int npart)
{
    __shared__ unsigned short tile[64][65];
    const int t = threadIdx.x, sub = t >> 6, lane = t & 63;
    const int b = blockIdx.y;
    const int n0 = blockIdx.x * 64;
    const unsigned short* src = seqbf + ((size_t)b * N + n0) * 64;
    #pragma unroll
    for (int rr = 0; rr < 16; ++rr) {
        const int r = rr * 4 + sub;
        tile[r][lane] = src[r * 64 + lane];
    }
    float Sv = 0.f;
    for (int p = 0; p < npart; ++p)
        Sv += Spart[(size_t)p * BN + b * N + n0 + lane];
    const float g = Sv > 0.f ? 1.f / Sv : 0.f;
    __syncthreads();
    unsigned short* dstb = seqTg + (size_t)b * 64 * N;
    #pragma unroll
    for (int ff = 0; ff < 16; ++ff) {
        const int f = ff * 4 + sub;
        const float v = bf2f(tile[lane][f]) * g;
        dstb[(size_t)f * N + n0 + lane] = f2bf(v);
    }
}

__device__ __forceinline__ float wexp(float f1, float F2i) {
    const float u = f1 + F2i;
    const float mx = fmaxf(u, 0.01f * u);
    return __builtin_amdgcn_exp2f(mx);
}

// Kernel 4: out = elu(coefs @ seqTg). (R4 structure, amplified REP x for measurement.)
__global__ __launch_bounds__(256) void k_attn_mm(
    const unsigned long long* __restrict__ mask,
    const float* __restrict__ F1, const float* __restrict__ F2,
    const unsigned short* __restrict__ seqTg,
    float* __restrict__ out, int N)
{
    __shared__ float part[4][1024];
    const int t = threadIdx.x, w = t >> 6, l = t & 63;
    const int b = blockIdx.y;
    const int i0 = blockIdx.x * 16;
    const int mrow = l & 15;
    const int koff = l >> 4;
    const int i = i0 + mrow;
    const float F2i = F2[b * N + i];
    const float* __restrict__ F1b = F1 + b * N;
    const unsigned long long* __restrict__ mrowp = mask + (size_t)(b * N + i) * 64;
    const unsigned short* __restrict__ Tb = seqTg + (size_t)b * 64 * N;
    f32x4 acc0 = {0.f, 0.f, 0.f, 0.f}, acc1 = acc0, acc2 = acc0, acc3 = acc0;
    const int kq0 = w * (N >> 2);
    #pragma unroll 1
    for (int rep = 0; rep < REP; ++rep) {
    for (int kc = 0; kc < (N >> 10); ++kc) {
        const int jb_base = kq0 + kc * 256;
        const unsigned long long* mw = mrowp + ((jb_base >> 8) << 2);
        const unsigned long long mw0 = mw[0], mw1 = mw[1], mw2 = mw[2], mw3 = mw[3];
        #pragma unroll
        for (int r = 0; r < 8; ++r) {
            const int j0l = jb_base + r * 32 + koff * 8;
            const int sb = r * 8 + koff * 2;
            const unsigned sh0 = (unsigned)(mw0 >> sb);
            const unsigned sh1 = (unsigned)(mw1 >> sb);
            const unsigned sh2 = (unsigned)(mw2 >> sb);
            const unsigned sh3 = (unsigned)(mw3 >> sb);
            const float4 fa = *(const float4*)(F1b + j0l);
            const float4 fbv = *(const float4*)(F1b + j0l + 4);
            unsigned pw[8];
            pw[0] = __float_as_uint(wexp(fa.x, F2i)) & (0u - (sh0 & 1u));
            pw[1] = __float_as_uint(wexp(fa.y, F2i)) & (0u - (sh1 & 1u));
            pw[2] = __float_as_uint(wexp(fa.z, F2i)) & (0u - (sh2 & 1u));
            pw[3] = __float_as_uint(wexp(fa.w, F2i)) & (0u - (sh3 & 1u));
            pw[4] = __float_as_uint(wexp(fbv.x, F2i)) & (0u - ((sh0 >> 1) & 1u));
            pw[5] = __float_as_uint(wexp(fbv.y, F2i)) & (0u - ((sh1 >> 1) & 1u));
            pw[6] = __float_as_uint(wexp(fbv.z, F2i)) & (0u - ((sh2 >> 1) & 1u));
            pw[7] = __float_as_uint(wexp(fbv.w, F2i)) & (0u - ((sh3 >> 1) & 1u));
            u32x4 aw;
            aw.x = __builtin_amdgcn_perm(pw[1], pw[0], 0x07060302u);
            aw.y = __builtin_amdgcn_perm(pw[3], pw[2], 0x07060302u);
            aw.z = __builtin_amdgcn_perm(pw[5], pw[4], 0x07060302u);
            aw.w = __builtin_amdgcn_perm(pw[7], pw[6], 0x07060302u);
            const short8 afrag = __builtin_bit_cast(short8, aw);
            const short8 b0 = *(const short8*)(Tb + (size_t)(0 * 16 + mrow) * N + j0l);
            const short8 b1 = *(const short8*)(Tb + (size_t)(1 * 16 + mrow) * N + j0l);
            const short8 b2 = *(const short8*)(Tb + (size_t)(2 * 16 + mrow) * N + j0l);
            const short8 b3 = *(const short8*)(Tb + (size_t)(3 * 16 + mrow) * N + j0l);
            acc0 = __builtin_amdgcn_mfma_f32_16x16x32_bf16(afrag, b0, acc0, 0, 0, 0);
            acc1 = __builtin_amdgcn_mfma_f32_16x16x32_bf16(afrag, b1, acc1, 0, 0, 0);
            acc2 = __builtin_amdgcn_mfma_f32_16x16x32_bf16(afrag, b2, acc2, 0, 0, 0);
            acc3 = __builtin_amdgcn_mfma_f32_16x16x32_bf16(afrag, b3, acc3, 0, 0, 0);
        }
    }
    }
    #pragma unroll
    for (int rg = 0; rg < 4; ++rg) {
        const int m = koff * 4 + rg;
        part[w][m * 64 + 0 * 16 + mrow] = acc0[rg] * REPSCALE;
        part[w][m * 64 + 1 * 16 + mrow] = acc1[rg] * REPSCALE;
        part[w][m * 64 + 2 * 16 + mrow] = acc2[rg] * REPSCALE;
        part[w][m * 64 + 3 * 16 + mrow] = acc3[rg] * REPSCALE;
    }
    __syncthreads();
    const float4 v0 = *(const float4*)&part[0][t * 4];
    const float4 v1 = *(const float4*)&part[1][t * 4];
    const float4 v2 = *(const float4*)&part[2][t * 4];
    const float4 v3 = *(const float4*)&part[3][t * 4];
    float4 r;
    r.x = v0.x + v1.x + v2.x + v3.x;
    r.y = v0.y + v1.y + v2.y + v3.y;
    r.z = v0.z + v1.z + v2.z + v3.z;
    r.w = v0.w + v1.w + v2.w + v3.w;
    r.x = r.x > 0.f ? r.x : __builtin_amdgcn_exp2f(r.x * LOG2E) - 1.f;
    r.y = r.y > 0.f ? r.y : __builtin_amdgcn_exp2f(r.y * LOG2E) - 1.f;
    r.z = r.z > 0.f ? r.z : __builtin_amdgcn_exp2f(r.z * LOG2E) - 1.f;
    r.w = r.w > 0.f ? r.w : __builtin_amdgcn_exp2f(r.w * LOG2E) - 1.f;
    *(float4*)(out + (size_t)(b * N + i0) * 64 + t * 4) = r;
}

extern "C" void kernel_launch(void* const* d_in, const int* in_sizes, int n_in,
                              void* d_out, int out_size, void* d_ws, size_t ws_size,
                              hipStream_t stream) {
    const float* x   = (const float*)d_in[0];
    const int*   adj = (const int*)d_in[1];
    const float* W1  = (const float*)d_in[2];
    const float* b1  = (const float*)d_in[3];
    const float* a1  = (const float*)d_in[4];
    const float* ba1 = (const float*)d_in[5];
    const float* a2  = (const float*)d_in[6];
    const float* ba2 = (const float*)d_in[7];
    float* out = (float*)d_out;

    const int F = in_sizes[3];                       // 64
    const int C = in_sizes[2] / F;                   // 64
    const long xs = in_sizes[0], as = in_sizes[1];
    const int N = (int)(as / (xs / C));              // 4096
    const int B = (int)(xs / ((long)N * C));         // 4
    const int BN = B * N;
    const int npart = N / 64;

    char* p = (char*)d_ws;
    unsigned short* seqbf = (unsigned short*)p; p += (size_t)BN * 64 * 2;
    unsigned short* seqTg = (unsigned short*)p; p += (size_t)BN * 64 * 2;
    float* F1 = (float*)p; p += (size_t)BN * 4;
    float* F2 = (float*)p; p += (size_t)BN * 4;
    float* Spart = (float*)p; p += (size_t)npart * BN * 4;
    unsigned long long* mask = (unsigned long long*)p; p += (size_t)BN * 64 * 8;

    k_feats<<<dim3(BN / 32), 256, 0, stream>>>(x, W1, b1, a1, ba1, a2, ba2, seqbf, F1, F2);
    k_stats<<<dim3(N / 64, N / 1024, B), 256, 0, stream>>>(adj, F1, F2, Spart, mask, N, BN);
    k_transpose<<<dim3(N / 64, B), 256, 0, stream>>>(seqbf, Spart, seqTg, N, BN, npart);
    k_attn_mm<<<dim3(N / 16, B), 256, 0, stream>>>(mask, F1, F2, seqTg, out, N);
}

// Round 7
// 109.504 us; speedup vs baseline: 7.8993x; 7.8993x over previous
//
#include <hip/hip_runtime.h>
#include <hip/hip_bf16.h>

typedef __attribute__((ext_vector_type(8))) short short8;
typedef __attribute__((ext_vector_type(4))) float f32x4;
typedef __attribute__((ext_vector_type(4))) unsigned int u32x4;

#define LOG2E 1.44269504088896f

__device__ __forceinline__ float bf2f(unsigned short b) {
    return __uint_as_float(((unsigned)b) << 16);
}
__device__ __forceinline__ unsigned short f2bf(float f) {
    __hip_bfloat16 h = __float2bfloat16(f);
    return __builtin_bit_cast(unsigned short, h);
}

// Kernel 1: seq_fts = x@W1 + b1 (f32, bf16 store) + F1/F2 row-dots via shuffle reduce.
__global__ __launch_bounds__(256) void k_feats(
    const float* __restrict__ x, const float* __restrict__ W1,
    const float* __restrict__ b1,
    const float* __restrict__ a1, const float* __restrict__ ba1,
    const float* __restrict__ a2, const float* __restrict__ ba2,
    unsigned short* __restrict__ seqbf,
    float* __restrict__ F1, float* __restrict__ F2)
{
    const int t = threadIdx.x, lane = t & 63;
    const int w = __builtin_amdgcn_readfirstlane(t >> 6);
    float W1r[64];
    #pragma unroll
    for (int c = 0; c < 64; ++c) W1r[c] = W1[c * 64 + lane];
    const float bias = b1[lane];
    const float a1l = a1[lane], a2l = a2[lane];
    const float bb1 = ba1[0], bb2 = ba2[0];
    const int row0 = (blockIdx.x * 4 + w) * 8;
    #pragma unroll
    for (int r = 0; r < 8; ++r) {
        const int row = row0 + r;
        const float* __restrict__ xr = x + (size_t)row * 64;
        float acc = bias;
        #pragma unroll
        for (int c = 0; c < 64; ++c) acc = fmaf(xr[c], W1r[c], acc);
        seqbf[(size_t)row * 64 + lane] = f2bf(acc);
        float r1 = acc * a1l;
        float r2 = acc * a2l;
        #pragma unroll
        for (int off = 32; off; off >>= 1) {
            r1 += __shfl_xor(r1, off);
            r2 += __shfl_xor(r2, off);
        }
        if (lane == 0) {
            F1[row] = LOG2E * (r1 + bb1);
            F2[row] = LOG2E * (r2 + bb2);
        }
    }
}

// Kernel 2: read adj once; bitmask + per-block partial column sums (zero atomics).
// mask layout: [b][i][jg(0..15)][c(0..3)] u64; word (jg,c) bit l = adj[b][i][jg*256+4*l+c].
__global__ __launch_bounds__(256) void k_stats(
    const int* __restrict__ adj, const float* __restrict__ F1,
    const float* __restrict__ F2, float* __restrict__ Spart,
    unsigned long long* __restrict__ mask, int N, int BN)
{
    __shared__ unsigned long long lds_mask[64][16];
    const int t = threadIdx.x, lane = t & 63;
    const int w = __builtin_amdgcn_readfirstlane(t >> 6);
    const int b = blockIdx.z;
    const int i0 = blockIdx.x * 64;
    const int jbase = blockIdx.y * 1024 + t * 4;
    const int* __restrict__ adjb = adj + (size_t)b * N * N;
    const float* __restrict__ F2b = F2 + b * N;
    const float4 f1v = *(const float4*)(F1 + b * N + jbase);
    float acc0 = 0.f, acc1 = 0.f, acc2 = 0.f, acc3 = 0.f;
    #pragma unroll 8
    for (int ii = 0; ii < 64; ++ii) {
        const int i = i0 + ii;
        const int4 a = *(const int4*)(adjb + (size_t)i * N + jbase);
        const float f2i = F2b[i];
        const unsigned long long m0 = __ballot(a.x > 0);
        const unsigned long long m1 = __ballot(a.y > 0);
        const unsigned long long m2 = __ballot(a.z > 0);
        const unsigned long long m3 = __ballot(a.w > 0);
        float u, mx;
        u = f1v.x + f2i; mx = fmaxf(u, 0.01f * u);
        acc0 += (a.x > 0) ? __builtin_amdgcn_exp2f(mx) : 0.f;
        u = f1v.y + f2i; mx = fmaxf(u, 0.01f * u);
        acc1 += (a.y > 0) ? __builtin_amdgcn_exp2f(mx) : 0.f;
        u = f1v.z + f2i; mx = fmaxf(u, 0.01f * u);
        acc2 += (a.z > 0) ? __builtin_amdgcn_exp2f(mx) : 0.f;
        u = f1v.w + f2i; mx = fmaxf(u, 0.01f * u);
        acc3 += (a.w > 0) ? __builtin_amdgcn_exp2f(mx) : 0.f;
        if (lane == 0) {
            lds_mask[ii][w * 4 + 0] = m0;
            lds_mask[ii][w * 4 + 1] = m1;
            lds_mask[ii][w * 4 + 2] = m2;
            lds_mask[ii][w * 4 + 3] = m3;
        }
    }
    float4 s4; s4.x = acc0; s4.y = acc1; s4.z = acc2; s4.w = acc3;
    *(float4*)(Spart + (size_t)blockIdx.x * BN + b * N + jbase) = s4;
    __syncthreads();
    {
        const int ii = t >> 2, q = t & 3;
        unsigned long long* __restrict__ maskb = mask + (size_t)b * N * 64;
        unsigned long long* dst = maskb + (size_t)(i0 + ii) * 64 + blockIdx.y * 16 + q * 4;
        const unsigned long long* src = &lds_mask[ii][q * 4];
        dst[0] = src[0]; dst[1] = src[1]; dst[2] = src[2]; dst[3] = src[3];
    }
}

// Kernel 3: S = sum of Spart partials; emit Tbp in PRE-SWIZZLED MFMA B-fragment order:
// Tbp[b][jblk][q][lane][e] = seq_fts[b][ jblk*32 + (lane>>4)*8 + e ][ (lane&15) + 16q ] / S[j]
// so k_attn_mm's 4 B-loads per 32-j block are each 64 lanes x 16B fully contiguous (1KB).
__global__ __launch_bounds__(256) void k_transpose(
    const unsigned short* __restrict__ seqbf, const float* __restrict__ Spart,
    unsigned short* __restrict__ Tbp, int N, int BN, int npart)
{
    __shared__ unsigned short tile[64][65];
    __shared__ float svp[4][64];
    __shared__ float gl[64];
    const int t = threadIdx.x, sub = t >> 6, lane = t & 63;
    const int b = blockIdx.y;
    const int n0 = blockIdx.x * 64;
    const unsigned short* src = seqbf + ((size_t)b * N + n0) * 64;
    #pragma unroll
    for (int rr = 0; rr < 16; ++rr) {
        const int r = rr * 4 + sub;
        tile[r][lane] = src[r * 64 + lane];
    }
    // column-sum S: thread sums its 16 partials for column j = n0+lane
    float sv = 0.f;
    const int p0 = sub * (npart >> 2);
    for (int p = 0; p < (npart >> 2); ++p)
        sv += Spart[(size_t)(p0 + p) * BN + b * N + n0 + lane];
    svp[sub][lane] = sv;
    __syncthreads();
    if (t < 64) {
        const float S = svp[0][t] + svp[1][t] + svp[2][t] + svp[3][t];
        gl[t] = S > 0.f ? 1.f / S : 0.f;
    }
    __syncthreads();
    const int q = sub;                       // f-quadrant
    const int koff = lane >> 4, mrow = lane & 15;
    const int ff = mrow + q * 16;
    unsigned short* __restrict__ Tp = Tbp + (size_t)b * (N >> 5) * 2048;
    #pragma unroll
    for (int jl = 0; jl < 2; ++jl) {
        short8 v;
        #pragma unroll
        for (int e = 0; e < 8; ++e) {
            const int jj = jl * 32 + koff * 8 + e;
            v[e] = (short)f2bf(bf2f(tile[jj][ff]) * gl[jj]);
        }
        const size_t jblk = (size_t)(n0 >> 5) + jl;
        *(short8*)(Tp + (jblk * 4 + q) * 512 + lane * 8) = v;
    }
}

__device__ __forceinline__ float wexp(float f1, float F2i) {
    const float u = f1 + F2i;
    const float mx = fmaxf(u, 0.01f * u);
    return __builtin_amdgcn_exp2f(mx);
}

// Kernel 4: out[b][i][f] = elu( sum_j w[i,j] * V'[j][f] ). 8 waves (K split 8-ways,
// 100% occupancy target), B-operand loads coalesced via pre-swizzled Tbp.
__global__ __launch_bounds__(512, 8) void k_attn_mm(
    const unsigned long long* __restrict__ mask,
    const float* __restrict__ F1, const float* __restrict__ F2,
    const unsigned short* __restrict__ Tbp,
    float* __restrict__ out, int N)
{
    __shared__ float part[8][1024];
    const int t = threadIdx.x, w = t >> 6, l = t & 63;
    const int b = blockIdx.y;
    const int i0 = blockIdx.x * 16;
    const int mrow = l & 15;
    const int koff = l >> 4;
    const int i = i0 + mrow;
    const float F2i = F2[b * N + i];
    const float* __restrict__ F1b = F1 + b * N;
    const unsigned long long* __restrict__ mrowp = mask + (size_t)(b * N + i) * 64;
    const unsigned short* __restrict__ Tp = Tbp + (size_t)b * (N >> 5) * 2048;
    f32x4 acc0 = {0.f, 0.f, 0.f, 0.f}, acc1 = acc0, acc2 = acc0, acc3 = acc0;
    #pragma unroll
    for (int kc = 0; kc < 2; ++kc) {
        const int jg = w * 2 + kc;           // 256-j group owned by this wave
        const unsigned long long* mw = mrowp + jg * 4;
        const unsigned long long mw0 = mw[0], mw1 = mw[1], mw2 = mw[2], mw3 = mw[3];
        #pragma unroll
        for (int r = 0; r < 8; ++r) {
            const int j0l = jg * 256 + r * 32 + koff * 8;
            const int sb = r * 8 + koff * 2;
            const unsigned sh0 = (unsigned)(mw0 >> sb);
            const unsigned sh1 = (unsigned)(mw1 >> sb);
            const unsigned sh2 = (unsigned)(mw2 >> sb);
            const unsigned sh3 = (unsigned)(mw3 >> sb);
            const float4 fa = *(const float4*)(F1b + j0l);
            const float4 fbv = *(const float4*)(F1b + j0l + 4);
            unsigned pw[8];
            pw[0] = __float_as_uint(wexp(fa.x, F2i)) & (0u - (sh0 & 1u));
            pw[1] = __float_as_uint(wexp(fa.y, F2i)) & (0u - (sh1 & 1u));
            pw[2] = __float_as_uint(wexp(fa.z, F2i)) & (0u - (sh2 & 1u));
            pw[3] = __float_as_uint(wexp(fa.w, F2i)) & (0u - (sh3 & 1u));
            pw[4] = __float_as_uint(wexp(fbv.x, F2i)) & (0u - ((sh0 >> 1) & 1u));
            pw[5] = __float_as_uint(wexp(fbv.y, F2i)) & (0u - ((sh1 >> 1) & 1u));
            pw[6] = __float_as_uint(wexp(fbv.z, F2i)) & (0u - ((sh2 >> 1) & 1u));
            pw[7] = __float_as_uint(wexp(fbv.w, F2i)) & (0u - ((sh3 >> 1) & 1u));
            u32x4 aw;
            aw.x = __builtin_amdgcn_perm(pw[1], pw[0], 0x07060302u);
            aw.y = __builtin_amdgcn_perm(pw[3], pw[2], 0x07060302u);
            aw.z = __builtin_amdgcn_perm(pw[5], pw[4], 0x07060302u);
            aw.w = __builtin_amdgcn_perm(pw[7], pw[6], 0x07060302u);
            const short8 afrag = __builtin_bit_cast(short8, aw);
            const unsigned short* tb = Tp + ((size_t)(jg * 8 + r) * 4) * 512 + l * 8;
            const short8 b0 = *(const short8*)(tb);
            const short8 b1 = *(const short8*)(tb + 512);
            const short8 b2 = *(const short8*)(tb + 1024);
            const short8 b3 = *(const short8*)(tb + 1536);
            acc0 = __builtin_amdgcn_mfma_f32_16x16x32_bf16(afrag, b0, acc0, 0, 0, 0);
            acc1 = __builtin_amdgcn_mfma_f32_16x16x32_bf16(afrag, b1, acc1, 0, 0, 0);
            acc2 = __builtin_amdgcn_mfma_f32_16x16x32_bf16(afrag, b2, acc2, 0, 0, 0);
            acc3 = __builtin_amdgcn_mfma_f32_16x16x32_bf16(afrag, b3, acc3, 0, 0, 0);
        }
    }
    #pragma unroll
    for (int rg = 0; rg < 4; ++rg) {
        const int m = koff * 4 + rg;
        part[w][m * 64 + 0 * 16 + mrow] = acc0[rg];
        part[w][m * 64 + 1 * 16 + mrow] = acc1[rg];
        part[w][m * 64 + 2 * 16 + mrow] = acc2[rg];
        part[w][m * 64 + 3 * 16 + mrow] = acc3[rg];
    }
    __syncthreads();
    const int e0 = t * 2;
    float s0 = 0.f, s1 = 0.f;
    #pragma unroll
    for (int p = 0; p < 8; ++p) {
        s0 += part[p][e0];
        s1 += part[p][e0 + 1];
    }
    float2 r;
    r.x = s0 > 0.f ? s0 : __builtin_amdgcn_exp2f(s0 * LOG2E) - 1.f;
    r.y = s1 > 0.f ? s1 : __builtin_amdgcn_exp2f(s1 * LOG2E) - 1.f;
    *(float2*)(out + (size_t)(b * N + i0) * 64 + e0) = r;
}

extern "C" void kernel_launch(void* const* d_in, const int* in_sizes, int n_in,
                              void* d_out, int out_size, void* d_ws, size_t ws_size,
                              hipStream_t stream) {
    const float* x   = (const float*)d_in[0];
    const int*   adj = (const int*)d_in[1];
    const float* W1  = (const float*)d_in[2];
    const float* b1  = (const float*)d_in[3];
    const float* a1  = (const float*)d_in[4];
    const float* ba1 = (const float*)d_in[5];
    const float* a2  = (const float*)d_in[6];
    const float* ba2 = (const float*)d_in[7];
    float* out = (float*)d_out;

    const int F = in_sizes[3];                       // 64
    const int C = in_sizes[2] / F;                   // 64
    const long xs = in_sizes[0], as = in_sizes[1];
    const int N = (int)(as / (xs / C));              // 4096
    const int B = (int)(xs / ((long)N * C));         // 4
    const int BN = B * N;
    const int npart = N / 64;

    char* p = (char*)d_ws;
    unsigned short* seqbf = (unsigned short*)p; p += (size_t)BN * 64 * 2;
    unsigned short* Tbp = (unsigned short*)p; p += (size_t)BN * 64 * 2;
    float* F1 = (float*)p; p += (size_t)BN * 4;
    float* F2 = (float*)p; p += (size_t)BN * 4;
    float* Spart = (float*)p; p += (size_t)npart * BN * 4;
    unsigned long long* mask = (unsigned long long*)p; p += (size_t)BN * 64 * 8;

    k_feats<<<dim3(BN / 32), 256, 0, stream>>>(x, W1, b1, a1, ba1, a2, ba2, seqbf, F1, F2);
    k_stats<<<dim3(N / 64, N / 1024, B), 256, 0, stream>>>(adj, F1, F2, Spart, mask, N, BN);
    k_transpose<<<dim3(N / 64, B), 256, 0, stream>>>(seqbf, Spart, Tbp, N, BN, npart);
    k_attn_mm<<<dim3(N / 16, B), 512, 0, stream>>>(mask, F1, F2, Tbp, out, N);
}